// Round 8
// baseline (196.960 us; speedup 1.0000x reference)
//
#include <hip/hip_runtime.h>

// ---------------------------------------------------------------------------
// QoSNet: gather -> 32-step GRU(D=128) -> batchnorm -> 3x SELU MLP readout
// BS=8192, N_LINKS=512, MAX_LEN=32, D_PATH=128, D_READ=256, N_OUT=3.
// R20 = R19 + ONE isolated change: kgru wave width 16ch -> 32ch.
//   - 4 waves x 256-thr blocks (was 8 x 512): each wave owns TWO 16-col
//     gate slices (ch = w*32 + s*16 + lm) and reuses one 5xb128 A-load for
//     30 MFMAs instead of 15.  Per-CU-step duplicated LDS reads halve
//     (80 KB -> 40 KB through the 128 B/cy pipe, ~625 -> ~310 cy), and the
//     per-step barrier spans 4 waves instead of 8.
//   - weight fragments double (~120 VGPR) -> __launch_bounds__(256,2) so
//     the allocator can use up to 256 VGPR without spilling.  Spill
//     tripwire: WRITE_SIZE must stay ~4.6 MB (R15's spill showed +20 MB).
//   - MFMA orientation/mapping byte-identical to R19 (mfma(a, W, acc),
//     A row = lm = item, C row = qd*4+r = item, C col = lm -> ch).
// R19 kept: raw v_exp_f32 gates.  R18 kept: feats f16x4 register prefetch.
// R16 base: R13 structure + exp2-folded gates + packed f16x4 feats.
// prep_all / kmlp: R16 verbatim.
// Known fixed floor: ~100 us of harness-side timed overhead (43 us of it is
// the 268 MB ws re-poison fill visible in rocprof).  absmax flips between
// 0.0625/0.125 across runs via BN float-atomic order -- not a regression.
// ---------------------------------------------------------------------------

#define BS 8192
#define NL 512
#define ML 32
#define DP 128
#define DR 256
#define NJOB 512             // 16 items per job
#define ST 172               // LDS row stride (f16) for K=160 + pad

// workspace layout (float offsets into d_ws)
#define OFF_SUM    64
#define OFF_SSQ    192
#define OFF_CUR    576
#define OFF_PERM   640                      // BS ints
#define OFF_WHH16  (OFF_PERM + BS)          // 49152 f16  = 24576 fl
#define OFF_W1     (OFF_WHH16 + 24576)      // 98304 f16  = 49152 fl
#define OFF_W2     (OFF_W1 + 49152)         // 196608 f16 = 98304 fl
#define OFF_FEATS  (OFF_W2 + 98304)         // BS*ML f16x4 = 2 MB
#define OFF_FLOW   (OFF_FEATS + BS*ML*4)    // BS*DP fl

// prep_all role partition (256-thr blocks)
#define FEATS_BLOCKS 1024
#define MAX_BLOCKS   256
#define WPREP_BLOCKS 336     // 344064 f16 elements / (256 thr * 4 per thread)
#define SORT_BID     (FEATS_BLOCKS + MAX_BLOCKS + WPREP_BLOCKS)   // 1616
#define PREP_GRID    (SORT_BID + 1)

#define KS (-1.44269504088896340736f)   // -log2(e): sigmoid arg scale
#define KT ( 2.88539008177792681472f)   //  2*log2(e): tanh arg scale

typedef _Float16 f16x8 __attribute__((ext_vector_type(8)));
typedef _Float16 f16x4 __attribute__((ext_vector_type(4)));
typedef float    f32x4 __attribute__((ext_vector_type(4)));

// raw hardware exp2 (v_exp_f32, no libm range fixup)
__device__ __forceinline__ float exp2_raw_(float x){
#if __has_builtin(__builtin_amdgcn_exp2f)
  return __builtin_amdgcn_exp2f(x);
#else
  return exp2f(x);
#endif
}

// gate helpers: args arrive pre-scaled by KS / KT via the weight tables
__device__ __forceinline__ float sig2_(float x){      // x = -log2e * s
  return __builtin_amdgcn_rcpf(1.0f + exp2_raw_(x));
}
__device__ __forceinline__ float tanh2_(float v){     // v = 2*log2e * u
  return fmaf(-2.0f, __builtin_amdgcn_rcpf(1.0f + exp2_raw_(v)), 1.0f);
}
__device__ __forceinline__ float seluf_(float x){
  const float sc = 1.0507009873554805f, al = 1.6732632423543772f;
  return x > 0.0f ? sc*x : sc*al*(__expf(x)-1.0f);
}

// ---------------------------------------------------------------------------
// prep_all: independent roles by blockIdx.x (R16 verbatim).
// ---------------------------------------------------------------------------
__global__ void prep_all(const int* __restrict__ path, const int* __restrict__ hop,
                         const float* __restrict__ avail, const float* __restrict__ capa,
                         const float* __restrict__ loss, const float* __restrict__ whh,
                         const float* __restrict__ rW1, const float* __restrict__ rW2,
                         float* ws){
  const int bid = blockIdx.x;
  const int tid = threadIdx.x;

  if (bid < FEATS_BLOCKS){                       // ---- feats gather (f16x4) ----
    int idx = bid*256 + tid;                     // over BS*ML
    int b = idx >> 5, t = idx & 31;
    f16x4 o = (f16x4)0;
    if (t < hop[b]){
      int l = path[idx];
      float a = avail[b*NL + l];
      float c = capa [b*NL + l];
      o[0] = (_Float16)a;
      o[1] = (_Float16)c;
      o[2] = (_Float16)(a / c);
      o[3] = (_Float16)loss[b*NL + l];
    }
    ((f16x4*)((_Float16*)(ws + OFF_FEATS)))[idx] = o;
  } else if (bid < FEATS_BLOCKS + MAX_BLOCKS){   // ---- global max(capa) ----
    const float4* c4 = (const float4*)capa;
    const int n4 = BS*NL/4;
    float m = 0.0f;
    for (int i = (bid - FEATS_BLOCKS)*256 + tid; i < n4; i += MAX_BLOCKS*256){
      float4 v = c4[i];
      m = fmaxf(m, fmaxf(fmaxf(v.x, v.y), fmaxf(v.z, v.w)));
    }
    #pragma unroll
    for (int o = 32; o > 0; o >>= 1) m = fmaxf(m, __shfl_down(m, o, 64));
    if ((tid & 63) == 0) atomicMax((int*)ws, __float_as_int(m));
  } else if (bid < SORT_BID){                    // ---- f16 weight tables ----
    _Float16* whh16 = (_Float16*)(ws + OFF_WHH16);
    _Float16* w1    = (_Float16*)(ws + OFF_W1);
    _Float16* w2    = (_Float16*)(ws + OFF_W2);
    int base = (bid - FEATS_BLOCKS - MAX_BLOCKS)*1024 + tid*4;
    if (base < 49152){
      // r/z rows (elems < 32768) pre-scaled by -log2e; n rows by 2log2e
      const float s = (base < 32768) ? KS : KT;
      const float4 v = *(const float4*)(whh + base);
      f16x4 o = { (_Float16)(v.x*s), (_Float16)(v.y*s),
                  (_Float16)(v.z*s), (_Float16)(v.w*s) };
      *(f16x4*)(whh16 + base) = o;
    } else if (base < 147456){
      int j = base - 49152; int u = j >> 15; int rem = j & 32767; int n = rem >> 7; int k = rem & 127;
      const float* src = rW1 + u*32768 + k*256 + n;   // k..k+3 same u,n (k%4==0)
      f16x4 o = { (_Float16)src[0], (_Float16)src[256], (_Float16)src[512], (_Float16)src[768] };
      *(f16x4*)(w1 + j) = o;
    } else {
      int j = base - 147456; int u = j >> 16; int rem = j & 65535; int n = rem >> 8; int k = rem & 255;
      const float* src = rW2 + u*65536 + k*256 + n;
      f16x4 o = { (_Float16)src[0], (_Float16)src[256], (_Float16)src[512], (_Float16)src[768] };
      *(f16x4*)(w2 + j) = o;
    }
  } else {                                       // ---- zero ctrl + hop sort ----
    __shared__ int hist[32], start[32];
    for (int i = 64 + tid; i < 640; i += 256) ws[i] = 0.0f;   // SUM/SSQ/CUR
    if (tid < 32) hist[tid] = 0;
    __syncthreads();
    for (int b = tid; b < BS; b += 256) atomicAdd(&hist[32 - hop[b]], 1);  // desc key
    __syncthreads();
    if (tid == 0){ int acc = 0; for (int i = 0; i < 32; ++i){ start[i] = acc; acc += hist[i]; } }
    __syncthreads();
    int* perm = (int*)ws + OFF_PERM;
    for (int b = tid; b < BS; b += 256){
      int pos = atomicAdd(&start[32 - hop[b]], 1);
      perm[pos] = b;
    }
  }
}

// ---------------------------------------------------------------------------
// GRU via MFMA, K=160 augmented A (cols 0..127 h, 128..131 feats, rest 0).
// R20: block = 256 thr = 4 waves; wave owns 32 ch as two 16-col slices
// (ch_s = w*32 + s*16 + lm).  One A-load (5x b128) feeds 30 MFMAs.
// Mapping per slice identical to R19: A row = lm = item, k = qd*8+j;
// C row = qd*4+r = item, C col = lm -> ch_s.
// Static LPT pairing: blocks i and 767-bid share a CU -> jobs i and 511-i.
// ---------------------------------------------------------------------------
__launch_bounds__(256, 2)
__global__ void kgru(const float* __restrict__ demand, const int* __restrict__ hop,
                     const float* __restrict__ wih, const float* __restrict__ bih,
                     const float* __restrict__ bhh, float* __restrict__ ws,
                     float* __restrict__ flow){
  __shared__ _Float16 hA[2][16*ST];
  const int tid  = threadIdx.x;
  const int w    = tid >> 6;          // 0..3
  const int lane = tid & 63;
  const int lm   = lane & 15;
  const int qd   = lane >> 4;
  const int ch0  = w*32 + lm;         // slice-0 channel
  const int ch1  = w*32 + 16 + lm;    // slice-1 channel
  const float inv_maxc = 1.0f / ws[0];
  const int* perm = (const int*)ws + OFF_PERM;
  const f16x4* feats16 = (const f16x4*)((const _Float16*)(ws + OFF_FEATS));
  const _Float16* whh16 = (const _Float16*)(ws + OFF_WHH16);

  const int bid = blockIdx.x;
  const int q = (bid < 256) ? bid : 767 - bid;   // LPT pair on shared CU

  // zero pad/feature cols 128..159, both buffers, before any feature write
  for (int idx = tid; idx < 1024; idx += 256){
    const int buf = idx >> 9;
    const int rem = idx & 511;
    const int m   = rem >> 5;
    const int c   = 128 + (rem & 31);
    hA[buf][m*ST + c] = (_Float16)0.f;
  }

  // B~ fragments for both slices (register-resident, pre-scaled whh16 table)
  f16x8 bfr[2][5], bfz[2][5], bfnh[2][4], bfni[2];
  #pragma unroll
  for (int s = 0; s < 2; ++s){
    const int chs = w*32 + s*16 + lm;
    #pragma unroll
    for (int kc = 0; kc < 4; ++kc){
      bfr[s][kc]  = *(const f16x8*)(whh16 + (      chs)*128 + kc*32 + qd*8);
      bfz[s][kc]  = *(const f16x8*)(whh16 + (128 + chs)*128 + kc*32 + qd*8);
      bfnh[s][kc] = *(const f16x8*)(whh16 + (256 + chs)*128 + kc*32 + qd*8);
    }
    bfr[s][4] = (f16x8)0; bfz[s][4] = (f16x8)0; bfni[s] = (f16x8)0;
    if (qd == 0){
      #pragma unroll
      for (int j = 0; j < 4; ++j){
        float sc = (j < 2) ? inv_maxc : 1.0f;
        bfr[s][4][j] = (_Float16)(wih[(      chs)*32 + 28 + j] * sc * KS);
        bfz[s][4][j] = (_Float16)(wih[(128 + chs)*32 + 28 + j] * sc * KS);
        bfni[s][j]   = (_Float16)(wih[(256 + chs)*32 + 28 + j] * sc * KT);
      }
    }
  }
  const float bR0  = (bih[ch0]     + bhh[ch0]    ) * KS;
  const float bR1  = (bih[ch1]     + bhh[ch1]    ) * KS;
  const float bZ0  = (bih[128+ch0] + bhh[128+ch0]) * KS;
  const float bZ1  = (bih[128+ch1] + bhh[128+ch1]) * KS;
  const float bNI0 = bih[256+ch0] * KT;
  const float bNI1 = bih[256+ch1] * KT;
  const float bNH0 = bhh[256+ch0] * KT;
  const float bNH1 = bhh[256+ch1] * KT;

  // job items (per quad: 4 items)
  int it[4], hp[4];
  #pragma unroll
  for (int r = 0; r < 4; ++r){
    it[r] = perm[q*16 + qd*4 + r];
    hp[r] = hop[it[r]];
  }
  int tmax = max(max(hp[0],hp[1]), max(hp[2],hp[3]));
  tmax = max(tmax, __shfl_xor(tmax, 16, 64));
  tmax = max(tmax, __shfl_xor(tmax, 32, 64));

  // feature-writer lanes: 4 per wave (item = w*4 + lane, one f16x4 each)
  const int  fw_i = w*4 + lane;
  const bool fw   = (lane < 4);
  const int  fw_b = fw ? perm[q*16 + fw_i] : 0;

  __syncthreads();   // pad zeroing complete before feature writes

  // init: h0 (both slices) + features(t=0); prime the feats pipeline
  float hprev0[4], hprev1[4];
  #pragma unroll
  for (int r = 0; r < 4; ++r){
    hprev0[r] = 0.0f;
    hprev1[r] = (ch1 == 127) ? demand[it[r]] * inv_maxc : 0.0f;
    hA[0][(qd*4 + r)*ST + ch0] = (_Float16)hprev0[r];
    hA[0][(qd*4 + r)*ST + ch1] = (_Float16)hprev1[r];
  }
  f16x4 fvreg = (f16x4)0;
  if (fw){
    *(f16x4*)(&hA[0][fw_i*ST + 128]) = feats16[fw_b*ML + 0];
    fvreg = feats16[fw_b*ML + 1];     // feats(t=1), retires during step 0
  }
  __syncthreads();

  for (int t = 0; t < tmax; ++t){
    const int cur = t & 1, nxt = cur ^ 1;
    if (fw){
      *(f16x4*)(&hA[nxt][fw_i*ST + 128]) = fvreg;   // feats(t+1), loaded at t-1
      int tn = t + 2; tn = (tn < ML) ? tn : (ML - 1);
      fvreg = feats16[fw_b*ML + tn];                // in flight across this step
    }

    // one A-load (5 x b128), used by both slices (30 MFMAs)
    f16x8 a[5];
    #pragma unroll
    for (int kc = 0; kc < 5; ++kc)
      a[kc] = *(const f16x8*)(&hA[cur][lm*ST + kc*32 + qd*8]);

    // ---- slice 0 ----
    {
      f32x4 accr  = {bR0, bR0, bR0, bR0};
      f32x4 accz  = {bZ0, bZ0, bZ0, bZ0};
      f32x4 accnh = {bNH0, bNH0, bNH0, bNH0};
      f32x4 accni = {bNI0, bNI0, bNI0, bNI0};
      #pragma unroll
      for (int kc = 0; kc < 5; ++kc){
        accr = __builtin_amdgcn_mfma_f32_16x16x32_f16(a[kc], bfr[0][kc], accr, 0, 0, 0);
        accz = __builtin_amdgcn_mfma_f32_16x16x32_f16(a[kc], bfz[0][kc], accz, 0, 0, 0);
        if (kc < 4)
          accnh = __builtin_amdgcn_mfma_f32_16x16x32_f16(a[kc], bfnh[0][kc], accnh, 0, 0, 0);
        else
          accni = __builtin_amdgcn_mfma_f32_16x16x32_f16(a[kc], bfni[0], accni, 0, 0, 0);
      }
      #pragma unroll
      for (int r = 0; r < 4; ++r){
        float rr = sig2_(accr[r]);
        float zz = sig2_(accz[r]);
        float nn = tanh2_(fmaf(rr, accnh[r], accni[r]));
        float hn = fmaf(zz, hprev0[r] - nn, nn);       // (1-z)*n + z*h
        if (t < hp[r]) hprev0[r] = hn;                 // freeze finished items
        hA[nxt][(qd*4 + r)*ST + ch0] = (_Float16)hprev0[r];
      }
    }
    // ---- slice 1 ----
    {
      f32x4 accr  = {bR1, bR1, bR1, bR1};
      f32x4 accz  = {bZ1, bZ1, bZ1, bZ1};
      f32x4 accnh = {bNH1, bNH1, bNH1, bNH1};
      f32x4 accni = {bNI1, bNI1, bNI1, bNI1};
      #pragma unroll
      for (int kc = 0; kc < 5; ++kc){
        accr = __builtin_amdgcn_mfma_f32_16x16x32_f16(a[kc], bfr[1][kc], accr, 0, 0, 0);
        accz = __builtin_amdgcn_mfma_f32_16x16x32_f16(a[kc], bfz[1][kc], accz, 0, 0, 0);
        if (kc < 4)
          accnh = __builtin_amdgcn_mfma_f32_16x16x32_f16(a[kc], bfnh[1][kc], accnh, 0, 0, 0);
        else
          accni = __builtin_amdgcn_mfma_f32_16x16x32_f16(a[kc], bfni[1], accni, 0, 0, 0);
      }
      #pragma unroll
      for (int r = 0; r < 4; ++r){
        float rr = sig2_(accr[r]);
        float zz = sig2_(accz[r]);
        float nn = tanh2_(fmaf(rr, accnh[r], accni[r]));
        float hn = fmaf(zz, hprev1[r] - nn, nn);       // (1-z)*n + z*h
        if (t < hp[r]) hprev1[r] = hn;                 // freeze finished items
        hA[nxt][(qd*4 + r)*ST + ch1] = (_Float16)hprev1[r];
      }
    }
    __syncthreads();
  }

  // flow write + BN partials (reduce over items = across qd for fixed lm)
  float s0 = 0.f, q0 = 0.f, s1 = 0.f, q1 = 0.f;
  #pragma unroll
  for (int r = 0; r < 4; ++r){
    float v0 = hprev0[r], v1 = hprev1[r];
    flow[it[r]*DP + ch0] = v0;
    flow[it[r]*DP + ch1] = v1;
    s0 += v0;  q0 = fmaf(v0, v0, q0);
    s1 += v1;  q1 = fmaf(v1, v1, q1);
  }
  s0 += __shfl_xor(s0, 16, 64);  s0 += __shfl_xor(s0, 32, 64);
  q0 += __shfl_xor(q0, 16, 64);  q0 += __shfl_xor(q0, 32, 64);
  s1 += __shfl_xor(s1, 16, 64);  s1 += __shfl_xor(s1, 32, 64);
  q1 += __shfl_xor(q1, 16, 64);  q1 += __shfl_xor(q1, 32, 64);
  if (qd == 0){
    atomicAdd(&ws[OFF_SUM + ch0], s0);
    atomicAdd(&ws[OFF_SSQ + ch0], q0);
    atomicAdd(&ws[OFF_SUM + ch1], s1);
    atomicAdd(&ws[OFF_SSQ + ch1], q1);
  }
}

// ---------------------------------------------------------------------------
// BN-finalize + 3-headed MLP via MFMA (R10 verbatim).
// ---------------------------------------------------------------------------
__launch_bounds__(256, 4)
__global__ void kmlp(const float* __restrict__ flow, const float* __restrict__ ws,
                     const float* __restrict__ gamma, const float* __restrict__ beta,
                     const float* __restrict__ rb1, const float* __restrict__ rb2,
                     const float* __restrict__ rW3, const float* __restrict__ rb3,
                     float* __restrict__ out){
  __shared__ _Float16 x_lds[32*136];
  __shared__ _Float16 h1_lds[32*264];
  __shared__ float aa[DP], bb[DP];
  __shared__ float y_part[4][32];
  const int tid  = threadIdx.x;
  const int w    = tid >> 6;
  const int lane = tid & 63;
  const int lm   = lane & 15;
  const int qd   = lane >> 4;
  const int b0   = blockIdx.x * 32;
  const int u    = blockIdx.y;
  const _Float16* w1 = (const _Float16*)(ws + OFF_W1) + u*(DR*DP);
  const _Float16* w2 = (const _Float16*)(ws + OFF_W2) + u*(DR*DR);

  if (tid < DP){                                // BN finalize (redundant/block)
    float m = ws[OFF_SUM + tid] * (1.0f/BS);
    float q = ws[OFF_SSQ + tid] * (1.0f/BS);
    float rstd = rsqrtf(q - m*m + 1e-5f);
    float a = rstd * gamma[tid];
    aa[tid] = a;
    bb[tid] = fmaf(-m, a, beta[tid]);
  }
  __syncthreads();

  for (int idx = tid; idx < 32*DP; idx += 256){
    int i = idx >> 7, h = idx & 127;
    x_lds[i*136 + h] = (_Float16)fmaf(flow[(b0 + i)*DP + h], aa[h], bb[h]);
  }
  __syncthreads();

  // ---- L1: 32x128 @ 128x256 -> selu -> h1_lds ----
  for (int nt = 0; nt < 4; ++nt){
    const int n = (4*w + nt)*16 + lm;
    const float bias1 = rb1[u*DR + n];
    f16x8 b1[4];
    #pragma unroll
    for (int kc = 0; kc < 4; ++kc)
      b1[kc] = *(const f16x8*)(w1 + n*DP + kc*32 + qd*8);
    #pragma unroll
    for (int mt = 0; mt < 2; ++mt){
      f32x4 acc = {bias1, bias1, bias1, bias1};
      #pragma unroll
      for (int kc = 0; kc < 4; ++kc){
        f16x8 a1 = *(const f16x8*)(&x_lds[(mt*16 + lm)*136 + kc*32 + qd*8]);
        acc = __builtin_amdgcn_mfma_f32_16x16x32_f16(a1, b1[kc], acc, 0, 0, 0);
      }
      #pragma unroll
      for (int r = 0; r < 4; ++r)
        h1_lds[(mt*16 + qd*4 + r)*264 + n] = (_Float16)seluf_(acc[r]);
    }
  }
  __syncthreads();

  // ---- L2: 32x256 @ 256x256 -> selu -> dot w3 (in-wave reduce) ----
  {
    float p[2][4] = {{0.f,0.f,0.f,0.f},{0.f,0.f,0.f,0.f}};
    for (int nt = 0; nt < 4; ++nt){
      const int n = (4*w + nt)*16 + lm;
      const float bias2 = rb2[u*DR + n];
      const float w3l   = rW3[u*DR + n];
      f16x8 b2[8];
      #pragma unroll
      for (int kc = 0; kc < 8; ++kc)
        b2[kc] = *(const f16x8*)(w2 + n*DR + kc*32 + qd*8);
      #pragma unroll
      for (int mt = 0; mt < 2; ++mt){
        f32x4 acc = {bias2, bias2, bias2, bias2};
        #pragma unroll
        for (int kc = 0; kc < 8; ++kc){
          f16x8 a2 = *(const f16x8*)(&h1_lds[(mt*16 + lm)*264 + kc*32 + qd*8]);
          acc = __builtin_amdgcn_mfma_f32_16x16x32_f16(a2, b2[kc], acc, 0, 0, 0);
        }
        #pragma unroll
        for (int r = 0; r < 4; ++r)
          p[mt][r] += seluf_(acc[r]) * w3l;
      }
    }
    #pragma unroll
    for (int mt = 0; mt < 2; ++mt){
      #pragma unroll
      for (int r = 0; r < 4; ++r){
        float v = p[mt][r];
        v += __shfl_xor(v, 1, 64);
        v += __shfl_xor(v, 2, 64);
        v += __shfl_xor(v, 4, 64);
        v += __shfl_xor(v, 8, 64);
        if (lm == 0) y_part[w][mt*16 + qd*4 + r] = v;
      }
    }
  }
  __syncthreads();
  if (tid < 32){
    float y = y_part[0][tid] + y_part[1][tid] + y_part[2][tid] + y_part[3][tid] + rb3[u];
    out[(b0 + tid)*3 + u] = y;
  }
}

extern "C" void kernel_launch(void* const* d_in, const int* in_sizes, int n_in,
                              void* d_out, int out_size, void* d_ws, size_t ws_size,
                              hipStream_t stream){
  const float* demand = (const float*)d_in[0];
  const float* avail  = (const float*)d_in[1];
  const float* capa   = (const float*)d_in[2];
  const float* loss   = (const float*)d_in[3];
  const int*   path   = (const int*)d_in[4];
  const int*   hop    = (const int*)d_in[5];
  const float* wih    = (const float*)d_in[6];
  const float* whh    = (const float*)d_in[7];
  const float* bih    = (const float*)d_in[8];
  const float* bhh    = (const float*)d_in[9];
  const float* gamma  = (const float*)d_in[10];
  const float* beta   = (const float*)d_in[11];
  const float* rW1    = (const float*)d_in[12];
  const float* rb1    = (const float*)d_in[13];
  const float* rW2    = (const float*)d_in[14];
  const float* rb2    = (const float*)d_in[15];
  const float* rW3    = (const float*)d_in[16];
  const float* rb3    = (const float*)d_in[17];
  float* ws  = (float*)d_ws;
  float* out = (float*)d_out;

  prep_all <<<PREP_GRID, 256, 0, stream>>>(path, hop, avail, capa, loss,
                                           whh, rW1, rW2, ws);
  kgru     <<<NJOB, 256, 0, stream>>>(demand, hop, wih, bih, bhh, ws, ws + OFF_FLOW);
  kmlp     <<<dim3(BS/32, 3), 256, 0, stream>>>(ws + OFF_FLOW, ws, gamma, beta,
                                                rb1, rb2, rW3, rb3, out);
}

// Round 9
// 191.118 us; speedup vs baseline: 1.0306x; 1.0306x over previous
//
#include <hip/hip_runtime.h>

// ---------------------------------------------------------------------------
// QoSNet: gather -> 32-step GRU(D=128) -> batchnorm -> 3x SELU MLP readout
// BS=8192, N_LINKS=512, MAX_LEN=32, D_PATH=128, D_READ=256, N_OUT=3.
// R21 = R20 + ONE isolated change: lane-ordered (coalesced) w1/w2 tables.
//   Old layout w[u][n][k] made kmlp's b1/b2 fragment loads 16 B/lane at a
//   512 B lane stride (64 separate 64 B lines per wave-load, 4x L2 traffic
//   amplification over 768 blocks).  New layout stores the exact per-lane
//   MFMA fragments contiguously: w1c[u][ngrp][kc][lane][8] (ngrp = n>>4,
//   lane = qd*16+lm), so each kmlp load instruction reads 64 x 16 B
//   contiguous.  Pure index permutation: same values, same rounding.
// kgru: R20 verbatim (32ch waves; neutral vs R19, kept).  R19 raw v_exp,
// R18 feats prefetch, R16 base retained.  prep feats/max/sort: verbatim.
// Known fixed floor: ~100 us of harness-side timed overhead (one 268 MB ws
// re-poison fill at ~43 us + ~20 small fills + ~30 launch gaps/iteration).
// absmax flips between 0.0625/0.125 across runs via BN float-atomic order.
// ---------------------------------------------------------------------------

#define BS 8192
#define NL 512
#define ML 32
#define DP 128
#define DR 256
#define NJOB 512             // 16 items per job
#define ST 172               // LDS row stride (f16) for K=160 + pad

// workspace layout (float offsets into d_ws)
#define OFF_SUM    64
#define OFF_SSQ    192
#define OFF_CUR    576
#define OFF_PERM   640                      // BS ints
#define OFF_WHH16  (OFF_PERM + BS)          // 49152 f16  = 24576 fl
#define OFF_W1     (OFF_WHH16 + 24576)      // 98304 f16  = 49152 fl
#define OFF_W2     (OFF_W1 + 49152)         // 196608 f16 = 98304 fl
#define OFF_FEATS  (OFF_W2 + 98304)         // BS*ML f16x4 = 2 MB
#define OFF_FLOW   (OFF_FEATS + BS*ML*4)    // BS*DP fl

// prep_all role partition (256-thr blocks)
#define FEATS_BLOCKS 1024
#define MAX_BLOCKS   256
#define WPREP_BLOCKS 336     // 344064 f16 elements / (256 thr * 4 per thread)
#define SORT_BID     (FEATS_BLOCKS + MAX_BLOCKS + WPREP_BLOCKS)   // 1616
#define PREP_GRID    (SORT_BID + 1)

#define KS (-1.44269504088896340736f)   // -log2(e): sigmoid arg scale
#define KT ( 2.88539008177792681472f)   //  2*log2(e): tanh arg scale

typedef _Float16 f16x8 __attribute__((ext_vector_type(8)));
typedef _Float16 f16x4 __attribute__((ext_vector_type(4)));
typedef float    f32x4 __attribute__((ext_vector_type(4)));

// raw hardware exp2 (v_exp_f32, no libm range fixup)
__device__ __forceinline__ float exp2_raw_(float x){
#if __has_builtin(__builtin_amdgcn_exp2f)
  return __builtin_amdgcn_exp2f(x);
#else
  return exp2f(x);
#endif
}

// gate helpers: args arrive pre-scaled by KS / KT via the weight tables
__device__ __forceinline__ float sig2_(float x){      // x = -log2e * s
  return __builtin_amdgcn_rcpf(1.0f + exp2_raw_(x));
}
__device__ __forceinline__ float tanh2_(float v){     // v = 2*log2e * u
  return fmaf(-2.0f, __builtin_amdgcn_rcpf(1.0f + exp2_raw_(v)), 1.0f);
}
__device__ __forceinline__ float seluf_(float x){
  const float sc = 1.0507009873554805f, al = 1.6732632423543772f;
  return x > 0.0f ? sc*x : sc*al*(__expf(x)-1.0f);
}

// ---------------------------------------------------------------------------
// prep_all: independent roles by blockIdx.x.
// R21: w1/w2 roles write lane-ordered fragment tiles (see header).
// ---------------------------------------------------------------------------
__global__ void prep_all(const int* __restrict__ path, const int* __restrict__ hop,
                         const float* __restrict__ avail, const float* __restrict__ capa,
                         const float* __restrict__ loss, const float* __restrict__ whh,
                         const float* __restrict__ rW1, const float* __restrict__ rW2,
                         float* ws){
  const int bid = blockIdx.x;
  const int tid = threadIdx.x;

  if (bid < FEATS_BLOCKS){                       // ---- feats gather (f16x4) ----
    int idx = bid*256 + tid;                     // over BS*ML
    int b = idx >> 5, t = idx & 31;
    f16x4 o = (f16x4)0;
    if (t < hop[b]){
      int l = path[idx];
      float a = avail[b*NL + l];
      float c = capa [b*NL + l];
      o[0] = (_Float16)a;
      o[1] = (_Float16)c;
      o[2] = (_Float16)(a / c);
      o[3] = (_Float16)loss[b*NL + l];
    }
    ((f16x4*)((_Float16*)(ws + OFF_FEATS)))[idx] = o;
  } else if (bid < FEATS_BLOCKS + MAX_BLOCKS){   // ---- global max(capa) ----
    const float4* c4 = (const float4*)capa;
    const int n4 = BS*NL/4;
    float m = 0.0f;
    for (int i = (bid - FEATS_BLOCKS)*256 + tid; i < n4; i += MAX_BLOCKS*256){
      float4 v = c4[i];
      m = fmaxf(m, fmaxf(fmaxf(v.x, v.y), fmaxf(v.z, v.w)));
    }
    #pragma unroll
    for (int o = 32; o > 0; o >>= 1) m = fmaxf(m, __shfl_down(m, o, 64));
    if ((tid & 63) == 0) atomicMax((int*)ws, __float_as_int(m));
  } else if (bid < SORT_BID){                    // ---- f16 weight tables ----
    _Float16* whh16 = (_Float16*)(ws + OFF_WHH16);
    _Float16* w1    = (_Float16*)(ws + OFF_W1);
    _Float16* w2    = (_Float16*)(ws + OFF_W2);
    int base = (bid - FEATS_BLOCKS - MAX_BLOCKS)*1024 + tid*4;
    if (base < 49152){
      // r/z rows (elems < 32768) pre-scaled by -log2e; n rows by 2log2e
      const float s = (base < 32768) ? KS : KT;
      const float4 v = *(const float4*)(whh + base);
      f16x4 o = { (_Float16)(v.x*s), (_Float16)(v.y*s),
                  (_Float16)(v.z*s), (_Float16)(v.w*s) };
      *(f16x4*)(whh16 + base) = o;
    } else if (base < 147456){
      // w1c[u][ngrp(16)][kc(4)][lane(64)][e(8)]:
      //   value = rW1[u][k=kc*32+(lane>>4)*8+e][n=ngrp*16+(lane&15)]
      int j = base - 49152;
      int u = j >> 15;        int rem  = j & 32767;
      int ngrp = rem >> 11;   int rem2 = rem & 2047;
      int kc   = rem2 >> 9;   int rem3 = rem2 & 511;
      int l    = rem3 >> 3;   int e0   = rem3 & 7;     // e0 in {0,4}
      int n = ngrp*16 + (l & 15);
      int k = kc*32 + (l >> 4)*8 + e0;
      const float* src = rW1 + u*32768 + k*256 + n;    // k..k+3 -> stride 256
      f16x4 o = { (_Float16)src[0], (_Float16)src[256], (_Float16)src[512], (_Float16)src[768] };
      *(f16x4*)(w1 + j) = o;
    } else {
      // w2c[u][ngrp(16)][kc(8)][lane(64)][e(8)]:
      //   value = rW2[u][k=kc*32+(lane>>4)*8+e][n=ngrp*16+(lane&15)]
      int j = base - 147456;
      int u = j >> 16;        int rem  = j & 65535;
      int ngrp = rem >> 12;   int rem2 = rem & 4095;
      int kc   = rem2 >> 9;   int rem3 = rem2 & 511;
      int l    = rem3 >> 3;   int e0   = rem3 & 7;
      int n = ngrp*16 + (l & 15);
      int k = kc*32 + (l >> 4)*8 + e0;
      const float* src = rW2 + u*65536 + k*256 + n;
      f16x4 o = { (_Float16)src[0], (_Float16)src[256], (_Float16)src[512], (_Float16)src[768] };
      *(f16x4*)(w2 + j) = o;
    }
  } else {                                       // ---- zero ctrl + hop sort ----
    __shared__ int hist[32], start[32];
    for (int i = 64 + tid; i < 640; i += 256) ws[i] = 0.0f;   // SUM/SSQ/CUR
    if (tid < 32) hist[tid] = 0;
    __syncthreads();
    for (int b = tid; b < BS; b += 256) atomicAdd(&hist[32 - hop[b]], 1);  // desc key
    __syncthreads();
    if (tid == 0){ int acc = 0; for (int i = 0; i < 32; ++i){ start[i] = acc; acc += hist[i]; } }
    __syncthreads();
    int* perm = (int*)ws + OFF_PERM;
    for (int b = tid; b < BS; b += 256){
      int pos = atomicAdd(&start[32 - hop[b]], 1);
      perm[pos] = b;
    }
  }
}

// ---------------------------------------------------------------------------
// GRU via MFMA, K=160 augmented A (cols 0..127 h, 128..131 feats, rest 0).
// R20: block = 256 thr = 4 waves; wave owns 32 ch as two 16-col slices
// (ch_s = w*32 + s*16 + lm).  One A-load (5x b128) feeds 30 MFMAs.
// Mapping per slice identical to R19: A row = lm = item, k = qd*8+j;
// C row = qd*4+r = item, C col = lm -> ch_s.
// Static LPT pairing: blocks i and 767-bid share a CU -> jobs i and 511-i.
// ---------------------------------------------------------------------------
__launch_bounds__(256, 2)
__global__ void kgru(const float* __restrict__ demand, const int* __restrict__ hop,
                     const float* __restrict__ wih, const float* __restrict__ bih,
                     const float* __restrict__ bhh, float* __restrict__ ws,
                     float* __restrict__ flow){
  __shared__ _Float16 hA[2][16*ST];
  const int tid  = threadIdx.x;
  const int w    = tid >> 6;          // 0..3
  const int lane = tid & 63;
  const int lm   = lane & 15;
  const int qd   = lane >> 4;
  const int ch0  = w*32 + lm;         // slice-0 channel
  const int ch1  = w*32 + 16 + lm;    // slice-1 channel
  const float inv_maxc = 1.0f / ws[0];
  const int* perm = (const int*)ws + OFF_PERM;
  const f16x4* feats16 = (const f16x4*)((const _Float16*)(ws + OFF_FEATS));
  const _Float16* whh16 = (const _Float16*)(ws + OFF_WHH16);

  const int bid = blockIdx.x;
  const int q = (bid < 256) ? bid : 767 - bid;   // LPT pair on shared CU

  // zero pad/feature cols 128..159, both buffers, before any feature write
  for (int idx = tid; idx < 1024; idx += 256){
    const int buf = idx >> 9;
    const int rem = idx & 511;
    const int m   = rem >> 5;
    const int c   = 128 + (rem & 31);
    hA[buf][m*ST + c] = (_Float16)0.f;
  }

  // B~ fragments for both slices (register-resident, pre-scaled whh16 table)
  f16x8 bfr[2][5], bfz[2][5], bfnh[2][4], bfni[2];
  #pragma unroll
  for (int s = 0; s < 2; ++s){
    const int chs = w*32 + s*16 + lm;
    #pragma unroll
    for (int kc = 0; kc < 4; ++kc){
      bfr[s][kc]  = *(const f16x8*)(whh16 + (      chs)*128 + kc*32 + qd*8);
      bfz[s][kc]  = *(const f16x8*)(whh16 + (128 + chs)*128 + kc*32 + qd*8);
      bfnh[s][kc] = *(const f16x8*)(whh16 + (256 + chs)*128 + kc*32 + qd*8);
    }
    bfr[s][4] = (f16x8)0; bfz[s][4] = (f16x8)0; bfni[s] = (f16x8)0;
    if (qd == 0){
      #pragma unroll
      for (int j = 0; j < 4; ++j){
        float sc = (j < 2) ? inv_maxc : 1.0f;
        bfr[s][4][j] = (_Float16)(wih[(      chs)*32 + 28 + j] * sc * KS);
        bfz[s][4][j] = (_Float16)(wih[(128 + chs)*32 + 28 + j] * sc * KS);
        bfni[s][j]   = (_Float16)(wih[(256 + chs)*32 + 28 + j] * sc * KT);
      }
    }
  }
  const float bR0  = (bih[ch0]     + bhh[ch0]    ) * KS;
  const float bR1  = (bih[ch1]     + bhh[ch1]    ) * KS;
  const float bZ0  = (bih[128+ch0] + bhh[128+ch0]) * KS;
  const float bZ1  = (bih[128+ch1] + bhh[128+ch1]) * KS;
  const float bNI0 = bih[256+ch0] * KT;
  const float bNI1 = bih[256+ch1] * KT;
  const float bNH0 = bhh[256+ch0] * KT;
  const float bNH1 = bhh[256+ch1] * KT;

  // job items (per quad: 4 items)
  int it[4], hp[4];
  #pragma unroll
  for (int r = 0; r < 4; ++r){
    it[r] = perm[q*16 + qd*4 + r];
    hp[r] = hop[it[r]];
  }
  int tmax = max(max(hp[0],hp[1]), max(hp[2],hp[3]));
  tmax = max(tmax, __shfl_xor(tmax, 16, 64));
  tmax = max(tmax, __shfl_xor(tmax, 32, 64));

  // feature-writer lanes: 4 per wave (item = w*4 + lane, one f16x4 each)
  const int  fw_i = w*4 + lane;
  const bool fw   = (lane < 4);
  const int  fw_b = fw ? perm[q*16 + fw_i] : 0;

  __syncthreads();   // pad zeroing complete before feature writes

  // init: h0 (both slices) + features(t=0); prime the feats pipeline
  float hprev0[4], hprev1[4];
  #pragma unroll
  for (int r = 0; r < 4; ++r){
    hprev0[r] = 0.0f;
    hprev1[r] = (ch1 == 127) ? demand[it[r]] * inv_maxc : 0.0f;
    hA[0][(qd*4 + r)*ST + ch0] = (_Float16)hprev0[r];
    hA[0][(qd*4 + r)*ST + ch1] = (_Float16)hprev1[r];
  }
  f16x4 fvreg = (f16x4)0;
  if (fw){
    *(f16x4*)(&hA[0][fw_i*ST + 128]) = feats16[fw_b*ML + 0];
    fvreg = feats16[fw_b*ML + 1];     // feats(t=1), retires during step 0
  }
  __syncthreads();

  for (int t = 0; t < tmax; ++t){
    const int cur = t & 1, nxt = cur ^ 1;
    if (fw){
      *(f16x4*)(&hA[nxt][fw_i*ST + 128]) = fvreg;   // feats(t+1), loaded at t-1
      int tn = t + 2; tn = (tn < ML) ? tn : (ML - 1);
      fvreg = feats16[fw_b*ML + tn];                // in flight across this step
    }

    // one A-load (5 x b128), used by both slices (30 MFMAs)
    f16x8 a[5];
    #pragma unroll
    for (int kc = 0; kc < 5; ++kc)
      a[kc] = *(const f16x8*)(&hA[cur][lm*ST + kc*32 + qd*8]);

    // ---- slice 0 ----
    {
      f32x4 accr  = {bR0, bR0, bR0, bR0};
      f32x4 accz  = {bZ0, bZ0, bZ0, bZ0};
      f32x4 accnh = {bNH0, bNH0, bNH0, bNH0};
      f32x4 accni = {bNI0, bNI0, bNI0, bNI0};
      #pragma unroll
      for (int kc = 0; kc < 5; ++kc){
        accr = __builtin_amdgcn_mfma_f32_16x16x32_f16(a[kc], bfr[0][kc], accr, 0, 0, 0);
        accz = __builtin_amdgcn_mfma_f32_16x16x32_f16(a[kc], bfz[0][kc], accz, 0, 0, 0);
        if (kc < 4)
          accnh = __builtin_amdgcn_mfma_f32_16x16x32_f16(a[kc], bfnh[0][kc], accnh, 0, 0, 0);
        else
          accni = __builtin_amdgcn_mfma_f32_16x16x32_f16(a[kc], bfni[0], accni, 0, 0, 0);
      }
      #pragma unroll
      for (int r = 0; r < 4; ++r){
        float rr = sig2_(accr[r]);
        float zz = sig2_(accz[r]);
        float nn = tanh2_(fmaf(rr, accnh[r], accni[r]));
        float hn = fmaf(zz, hprev0[r] - nn, nn);       // (1-z)*n + z*h
        if (t < hp[r]) hprev0[r] = hn;                 // freeze finished items
        hA[nxt][(qd*4 + r)*ST + ch0] = (_Float16)hprev0[r];
      }
    }
    // ---- slice 1 ----
    {
      f32x4 accr  = {bR1, bR1, bR1, bR1};
      f32x4 accz  = {bZ1, bZ1, bZ1, bZ1};
      f32x4 accnh = {bNH1, bNH1, bNH1, bNH1};
      f32x4 accni = {bNI1, bNI1, bNI1, bNI1};
      #pragma unroll
      for (int kc = 0; kc < 5; ++kc){
        accr = __builtin_amdgcn_mfma_f32_16x16x32_f16(a[kc], bfr[1][kc], accr, 0, 0, 0);
        accz = __builtin_amdgcn_mfma_f32_16x16x32_f16(a[kc], bfz[1][kc], accz, 0, 0, 0);
        if (kc < 4)
          accnh = __builtin_amdgcn_mfma_f32_16x16x32_f16(a[kc], bfnh[1][kc], accnh, 0, 0, 0);
        else
          accni = __builtin_amdgcn_mfma_f32_16x16x32_f16(a[kc], bfni[1], accni, 0, 0, 0);
      }
      #pragma unroll
      for (int r = 0; r < 4; ++r){
        float rr = sig2_(accr[r]);
        float zz = sig2_(accz[r]);
        float nn = tanh2_(fmaf(rr, accnh[r], accni[r]));
        float hn = fmaf(zz, hprev1[r] - nn, nn);       // (1-z)*n + z*h
        if (t < hp[r]) hprev1[r] = hn;                 // freeze finished items
        hA[nxt][(qd*4 + r)*ST + ch1] = (_Float16)hprev1[r];
      }
    }
    __syncthreads();
  }

  // flow write + BN partials (reduce over items = across qd for fixed lm)
  float s0 = 0.f, q0 = 0.f, s1 = 0.f, q1 = 0.f;
  #pragma unroll
  for (int r = 0; r < 4; ++r){
    float v0 = hprev0[r], v1 = hprev1[r];
    flow[it[r]*DP + ch0] = v0;
    flow[it[r]*DP + ch1] = v1;
    s0 += v0;  q0 = fmaf(v0, v0, q0);
    s1 += v1;  q1 = fmaf(v1, v1, q1);
  }
  s0 += __shfl_xor(s0, 16, 64);  s0 += __shfl_xor(s0, 32, 64);
  q0 += __shfl_xor(q0, 16, 64);  q0 += __shfl_xor(q0, 32, 64);
  s1 += __shfl_xor(s1, 16, 64);  s1 += __shfl_xor(s1, 32, 64);
  q1 += __shfl_xor(q1, 16, 64);  q1 += __shfl_xor(q1, 32, 64);
  if (qd == 0){
    atomicAdd(&ws[OFF_SUM + ch0], s0);
    atomicAdd(&ws[OFF_SSQ + ch0], q0);
    atomicAdd(&ws[OFF_SUM + ch1], s1);
    atomicAdd(&ws[OFF_SSQ + ch1], q1);
  }
}

// ---------------------------------------------------------------------------
// BN-finalize + 3-headed MLP via MFMA.
// R21: b1/b2 fragment loads use the lane-ordered w1c/w2c tables --
// 64 lanes x 16 B contiguous per load instruction.
// ---------------------------------------------------------------------------
__launch_bounds__(256, 4)
__global__ void kmlp(const float* __restrict__ flow, const float* __restrict__ ws,
                     const float* __restrict__ gamma, const float* __restrict__ beta,
                     const float* __restrict__ rb1, const float* __restrict__ rb2,
                     const float* __restrict__ rW3, const float* __restrict__ rb3,
                     float* __restrict__ out){
  __shared__ _Float16 x_lds[32*136];
  __shared__ _Float16 h1_lds[32*264];
  __shared__ float aa[DP], bb[DP];
  __shared__ float y_part[4][32];
  const int tid  = threadIdx.x;
  const int w    = tid >> 6;
  const int lane = tid & 63;
  const int lm   = lane & 15;
  const int qd   = lane >> 4;
  const int b0   = blockIdx.x * 32;
  const int u    = blockIdx.y;
  const _Float16* w1 = (const _Float16*)(ws + OFF_W1) + u*(DR*DP);
  const _Float16* w2 = (const _Float16*)(ws + OFF_W2) + u*(DR*DR);

  if (tid < DP){                                // BN finalize (redundant/block)
    float m = ws[OFF_SUM + tid] * (1.0f/BS);
    float q = ws[OFF_SSQ + tid] * (1.0f/BS);
    float rstd = rsqrtf(q - m*m + 1e-5f);
    float a = rstd * gamma[tid];
    aa[tid] = a;
    bb[tid] = fmaf(-m, a, beta[tid]);
  }
  __syncthreads();

  for (int idx = tid; idx < 32*DP; idx += 256){
    int i = idx >> 7, h = idx & 127;
    x_lds[i*136 + h] = (_Float16)fmaf(flow[(b0 + i)*DP + h], aa[h], bb[h]);
  }
  __syncthreads();

  // ---- L1: 32x128 @ 128x256 -> selu -> h1_lds ----
  for (int nt = 0; nt < 4; ++nt){
    const int ng = 4*w + nt;
    const int n  = ng*16 + lm;
    const float bias1 = rb1[u*DR + n];
    f16x8 b1[4];
    #pragma unroll
    for (int kc = 0; kc < 4; ++kc)
      b1[kc] = *(const f16x8*)(w1 + ((ng*4 + kc)*64 + lane)*8);
    #pragma unroll
    for (int mt = 0; mt < 2; ++mt){
      f32x4 acc = {bias1, bias1, bias1, bias1};
      #pragma unroll
      for (int kc = 0; kc < 4; ++kc){
        f16x8 a1 = *(const f16x8*)(&x_lds[(mt*16 + lm)*136 + kc*32 + qd*8]);
        acc = __builtin_amdgcn_mfma_f32_16x16x32_f16(a1, b1[kc], acc, 0, 0, 0);
      }
      #pragma unroll
      for (int r = 0; r < 4; ++r)
        h1_lds[(mt*16 + qd*4 + r)*264 + n] = (_Float16)seluf_(acc[r]);
    }
  }
  __syncthreads();

  // ---- L2: 32x256 @ 256x256 -> selu -> dot w3 (in-wave reduce) ----
  {
    float p[2][4] = {{0.f,0.f,0.f,0.f},{0.f,0.f,0.f,0.f}};
    for (int nt = 0; nt < 4; ++nt){
      const int ng = 4*w + nt;
      const int n  = ng*16 + lm;
      const float bias2 = rb2[u*DR + n];
      const float w3l   = rW3[u*DR + n];
      f16x8 b2[8];
      #pragma unroll
      for (int kc = 0; kc < 8; ++kc)
        b2[kc] = *(const f16x8*)(w2 + ((ng*8 + kc)*64 + lane)*8);
      #pragma unroll
      for (int mt = 0; mt < 2; ++mt){
        f32x4 acc = {bias2, bias2, bias2, bias2};
        #pragma unroll
        for (int kc = 0; kc < 8; ++kc){
          f16x8 a2 = *(const f16x8*)(&h1_lds[(mt*16 + lm)*264 + kc*32 + qd*8]);
          acc = __builtin_amdgcn_mfma_f32_16x16x32_f16(a2, b2[kc], acc, 0, 0, 0);
        }
        #pragma unroll
        for (int r = 0; r < 4; ++r)
          p[mt][r] += seluf_(acc[r]) * w3l;
      }
    }
    #pragma unroll
    for (int mt = 0; mt < 2; ++mt){
      #pragma unroll
      for (int r = 0; r < 4; ++r){
        float v = p[mt][r];
        v += __shfl_xor(v, 1, 64);
        v += __shfl_xor(v, 2, 64);
        v += __shfl_xor(v, 4, 64);
        v += __shfl_xor(v, 8, 64);
        if (lm == 0) y_part[w][mt*16 + qd*4 + r] = v;
      }
    }
  }
  __syncthreads();
  if (tid < 32){
    float y = y_part[0][tid] + y_part[1][tid] + y_part[2][tid] + y_part[3][tid] + rb3[u];
    out[(b0 + tid)*3 + u] = y;
  }
}

extern "C" void kernel_launch(void* const* d_in, const int* in_sizes, int n_in,
                              void* d_out, int out_size, void* d_ws, size_t ws_size,
                              hipStream_t stream){
  const float* demand = (const float*)d_in[0];
  const float* avail  = (const float*)d_in[1];
  const float* capa   = (const float*)d_in[2];
  const float* loss   = (const float*)d_in[3];
  const int*   path   = (const int*)d_in[4];
  const int*   hop    = (const int*)d_in[5];
  const float* wih    = (const float*)d_in[6];
  const float* whh    = (const float*)d_in[7];
  const float* bih    = (const float*)d_in[8];
  const float* bhh    = (const float*)d_in[9];
  const float* gamma  = (const float*)d_in[10];
  const float* beta   = (const float*)d_in[11];
  const float* rW1    = (const float*)d_in[12];
  const float* rb1    = (const float*)d_in[13];
  const float* rW2    = (const float*)d_in[14];
  const float* rb2    = (const float*)d_in[15];
  const float* rW3    = (const float*)d_in[16];
  const float* rb3    = (const float*)d_in[17];
  float* ws  = (float*)d_ws;
  float* out = (float*)d_out;

  prep_all <<<PREP_GRID, 256, 0, stream>>>(path, hop, avail, capa, loss,
                                           whh, rW1, rW2, ws);
  kgru     <<<NJOB, 256, 0, stream>>>(demand, hop, wih, bih, bhh, ws, ws + OFF_FLOW);
  kmlp     <<<dim3(BS/32, 3), 256, 0, stream>>>(ws + OFF_FLOW, ws, gamma, beta,
                                                rb1, rb2, rW3, rb3, out);
}

// Round 10
// 188.565 us; speedup vs baseline: 1.0445x; 1.0135x over previous
//
#include <hip/hip_runtime.h>

// ---------------------------------------------------------------------------
// QoSNet: gather -> 32-step GRU(D=128) -> batchnorm -> 3x SELU MLP readout
// BS=8192, N_LINKS=512, MAX_LEN=32, D_PATH=128, D_READ=256, N_OUT=3.
// R22 = R21 + ONE isolated change: parallel hop sort (32 blocks, 1/bucket).
//   Old: ONE 256-thr block did LDS-atomic histogram (8192 adds), a serial
//   32-bin prefix on tid0, and an atomic scatter -- a single-CU straggler
//   tail gating the kgru launch (~8-15 us est).  New: block v in [0,32)
//   owns hop value hv = 32-v; computes start_v = #items{hop > hv} by
//   count+block-reduce (no atomics), then scatters its bucket with a
//   block-local cursor.  Disjoint perm ranges partition [0,BS).  Bucket-
//   internal order changes (legal: jobs only need hop-desc grouping; BN
//   atomic order already wiggles absmax within the 0.0625-0.125 band).
// R21 kept: lane-ordered coalesced w1/w2 tables (kmlp -5.8 us confirmed).
// R20 kept: 32ch kgru waves.  R19: raw v_exp.  R18: feats prefetch.
// R16 base: R13 structure + exp2-folded gates + packed f16x4 feats.
// Known fixed floor: ~98 us harness-side timed overhead (268 MB ws fill at
// ~43 us + small fills + launch gaps).
// ---------------------------------------------------------------------------

#define BS 8192
#define NL 512
#define ML 32
#define DP 128
#define DR 256
#define NJOB 512             // 16 items per job
#define ST 172               // LDS row stride (f16) for K=160 + pad

// workspace layout (float offsets into d_ws)
#define OFF_SUM    64
#define OFF_SSQ    192
#define OFF_CUR    576
#define OFF_PERM   640                      // BS ints
#define OFF_WHH16  (OFF_PERM + BS)          // 49152 f16  = 24576 fl
#define OFF_W1     (OFF_WHH16 + 24576)      // 98304 f16  = 49152 fl
#define OFF_W2     (OFF_W1 + 49152)         // 196608 f16 = 98304 fl
#define OFF_FEATS  (OFF_W2 + 98304)         // BS*ML f16x4 = 2 MB
#define OFF_FLOW   (OFF_FEATS + BS*ML*4)    // BS*DP fl

// prep_all role partition (256-thr blocks)
#define FEATS_BLOCKS 1024
#define MAX_BLOCKS   256
#define WPREP_BLOCKS 336     // 344064 f16 elements / (256 thr * 4 per thread)
#define SORT_BID     (FEATS_BLOCKS + MAX_BLOCKS + WPREP_BLOCKS)   // 1616
#define SORT_BLOCKS  32
#define PREP_GRID    (SORT_BID + SORT_BLOCKS)

#define KS (-1.44269504088896340736f)   // -log2(e): sigmoid arg scale
#define KT ( 2.88539008177792681472f)   //  2*log2(e): tanh arg scale

typedef _Float16 f16x8 __attribute__((ext_vector_type(8)));
typedef _Float16 f16x4 __attribute__((ext_vector_type(4)));
typedef float    f32x4 __attribute__((ext_vector_type(4)));

// raw hardware exp2 (v_exp_f32, no libm range fixup)
__device__ __forceinline__ float exp2_raw_(float x){
#if __has_builtin(__builtin_amdgcn_exp2f)
  return __builtin_amdgcn_exp2f(x);
#else
  return exp2f(x);
#endif
}

// gate helpers: args arrive pre-scaled by KS / KT via the weight tables
__device__ __forceinline__ float sig2_(float x){      // x = -log2e * s
  return __builtin_amdgcn_rcpf(1.0f + exp2_raw_(x));
}
__device__ __forceinline__ float tanh2_(float v){     // v = 2*log2e * u
  return fmaf(-2.0f, __builtin_amdgcn_rcpf(1.0f + exp2_raw_(v)), 1.0f);
}
__device__ __forceinline__ float seluf_(float x){
  const float sc = 1.0507009873554805f, al = 1.6732632423543772f;
  return x > 0.0f ? sc*x : sc*al*(__expf(x)-1.0f);
}

// ---------------------------------------------------------------------------
// prep_all: independent roles by blockIdx.x.
// R22: sort role parallelized to 32 blocks (one per hop bucket).
// ---------------------------------------------------------------------------
__global__ void prep_all(const int* __restrict__ path, const int* __restrict__ hop,
                         const float* __restrict__ avail, const float* __restrict__ capa,
                         const float* __restrict__ loss, const float* __restrict__ whh,
                         const float* __restrict__ rW1, const float* __restrict__ rW2,
                         float* ws){
  const int bid = blockIdx.x;
  const int tid = threadIdx.x;

  if (bid < FEATS_BLOCKS){                       // ---- feats gather (f16x4) ----
    int idx = bid*256 + tid;                     // over BS*ML
    int b = idx >> 5, t = idx & 31;
    f16x4 o = (f16x4)0;
    if (t < hop[b]){
      int l = path[idx];
      float a = avail[b*NL + l];
      float c = capa [b*NL + l];
      o[0] = (_Float16)a;
      o[1] = (_Float16)c;
      o[2] = (_Float16)(a / c);
      o[3] = (_Float16)loss[b*NL + l];
    }
    ((f16x4*)((_Float16*)(ws + OFF_FEATS)))[idx] = o;
  } else if (bid < FEATS_BLOCKS + MAX_BLOCKS){   // ---- global max(capa) ----
    const float4* c4 = (const float4*)capa;
    const int n4 = BS*NL/4;
    float m = 0.0f;
    for (int i = (bid - FEATS_BLOCKS)*256 + tid; i < n4; i += MAX_BLOCKS*256){
      float4 v = c4[i];
      m = fmaxf(m, fmaxf(fmaxf(v.x, v.y), fmaxf(v.z, v.w)));
    }
    #pragma unroll
    for (int o = 32; o > 0; o >>= 1) m = fmaxf(m, __shfl_down(m, o, 64));
    if ((tid & 63) == 0) atomicMax((int*)ws, __float_as_int(m));
  } else if (bid < SORT_BID){                    // ---- f16 weight tables ----
    _Float16* whh16 = (_Float16*)(ws + OFF_WHH16);
    _Float16* w1    = (_Float16*)(ws + OFF_W1);
    _Float16* w2    = (_Float16*)(ws + OFF_W2);
    int base = (bid - FEATS_BLOCKS - MAX_BLOCKS)*1024 + tid*4;
    if (base < 49152){
      // r/z rows (elems < 32768) pre-scaled by -log2e; n rows by 2log2e
      const float s = (base < 32768) ? KS : KT;
      const float4 v = *(const float4*)(whh + base);
      f16x4 o = { (_Float16)(v.x*s), (_Float16)(v.y*s),
                  (_Float16)(v.z*s), (_Float16)(v.w*s) };
      *(f16x4*)(whh16 + base) = o;
    } else if (base < 147456){
      // w1c[u][ngrp(16)][kc(4)][lane(64)][e(8)]:
      //   value = rW1[u][k=kc*32+(lane>>4)*8+e][n=ngrp*16+(lane&15)]
      int j = base - 49152;
      int u = j >> 15;        int rem  = j & 32767;
      int ngrp = rem >> 11;   int rem2 = rem & 2047;
      int kc   = rem2 >> 9;   int rem3 = rem2 & 511;
      int l    = rem3 >> 3;   int e0   = rem3 & 7;     // e0 in {0,4}
      int n = ngrp*16 + (l & 15);
      int k = kc*32 + (l >> 4)*8 + e0;
      const float* src = rW1 + u*32768 + k*256 + n;    // k..k+3 -> stride 256
      f16x4 o = { (_Float16)src[0], (_Float16)src[256], (_Float16)src[512], (_Float16)src[768] };
      *(f16x4*)(w1 + j) = o;
    } else {
      // w2c[u][ngrp(16)][kc(8)][lane(64)][e(8)]:
      //   value = rW2[u][k=kc*32+(lane>>4)*8+e][n=ngrp*16+(lane&15)]
      int j = base - 147456;
      int u = j >> 16;        int rem  = j & 65535;
      int ngrp = rem >> 12;   int rem2 = rem & 4095;
      int kc   = rem2 >> 9;   int rem3 = rem2 & 511;
      int l    = rem3 >> 3;   int e0   = rem3 & 7;
      int n = ngrp*16 + (l & 15);
      int k = kc*32 + (l >> 4)*8 + e0;
      const float* src = rW2 + u*65536 + k*256 + n;
      f16x4 o = { (_Float16)src[0], (_Float16)src[256], (_Float16)src[512], (_Float16)src[768] };
      *(f16x4*)(w2 + j) = o;
    }
  } else {                                       // ---- zero ctrl + bucket scatter ----
    const int v  = bid - SORT_BID;               // key 0..31 (hop descending)
    const int hv = 32 - v;                       // this block's hop value
    __shared__ int wsum[4];
    __shared__ int cur;
    if (v == 0)
      for (int i = 64 + tid; i < 640; i += 256) ws[i] = 0.0f;   // SUM/SSQ/CUR
    // start_v = #items with hop > hv (lower keys precede this bucket)
    int cnt = 0;
    for (int b = tid; b < BS; b += 256) cnt += (hop[b] > hv) ? 1 : 0;
    #pragma unroll
    for (int o = 32; o > 0; o >>= 1) cnt += __shfl_down(cnt, o, 64);
    if ((tid & 63) == 0) wsum[tid >> 6] = cnt;
    if (tid == 0) cur = 0;
    __syncthreads();
    const int start_v = wsum[0] + wsum[1] + wsum[2] + wsum[3];
    int* perm = (int*)ws + OFF_PERM;
    for (int b = tid; b < BS; b += 256){
      if (hop[b] == hv){
        int p = atomicAdd(&cur, 1);
        perm[start_v + p] = b;
      }
    }
  }
}

// ---------------------------------------------------------------------------
// GRU via MFMA, K=160 augmented A (cols 0..127 h, 128..131 feats, rest 0).
// R20: block = 256 thr = 4 waves; wave owns 32 ch as two 16-col slices
// (ch_s = w*32 + s*16 + lm).  One A-load (5x b128) feeds 30 MFMAs.
// Mapping per slice identical to R19: A row = lm = item, k = qd*8+j;
// C row = qd*4+r = item, C col = lm -> ch_s.
// Static LPT pairing: blocks i and 767-bid share a CU -> jobs i and 511-i.
// ---------------------------------------------------------------------------
__launch_bounds__(256, 2)
__global__ void kgru(const float* __restrict__ demand, const int* __restrict__ hop,
                     const float* __restrict__ wih, const float* __restrict__ bih,
                     const float* __restrict__ bhh, float* __restrict__ ws,
                     float* __restrict__ flow){
  __shared__ _Float16 hA[2][16*ST];
  const int tid  = threadIdx.x;
  const int w    = tid >> 6;          // 0..3
  const int lane = tid & 63;
  const int lm   = lane & 15;
  const int qd   = lane >> 4;
  const int ch0  = w*32 + lm;         // slice-0 channel
  const int ch1  = w*32 + 16 + lm;    // slice-1 channel
  const float inv_maxc = 1.0f / ws[0];
  const int* perm = (const int*)ws + OFF_PERM;
  const f16x4* feats16 = (const f16x4*)((const _Float16*)(ws + OFF_FEATS));
  const _Float16* whh16 = (const _Float16*)(ws + OFF_WHH16);

  const int bid = blockIdx.x;
  const int q = (bid < 256) ? bid : 767 - bid;   // LPT pair on shared CU

  // zero pad/feature cols 128..159, both buffers, before any feature write
  for (int idx = tid; idx < 1024; idx += 256){
    const int buf = idx >> 9;
    const int rem = idx & 511;
    const int m   = rem >> 5;
    const int c   = 128 + (rem & 31);
    hA[buf][m*ST + c] = (_Float16)0.f;
  }

  // B~ fragments for both slices (register-resident, pre-scaled whh16 table)
  f16x8 bfr[2][5], bfz[2][5], bfnh[2][4], bfni[2];
  #pragma unroll
  for (int s = 0; s < 2; ++s){
    const int chs = w*32 + s*16 + lm;
    #pragma unroll
    for (int kc = 0; kc < 4; ++kc){
      bfr[s][kc]  = *(const f16x8*)(whh16 + (      chs)*128 + kc*32 + qd*8);
      bfz[s][kc]  = *(const f16x8*)(whh16 + (128 + chs)*128 + kc*32 + qd*8);
      bfnh[s][kc] = *(const f16x8*)(whh16 + (256 + chs)*128 + kc*32 + qd*8);
    }
    bfr[s][4] = (f16x8)0; bfz[s][4] = (f16x8)0; bfni[s] = (f16x8)0;
    if (qd == 0){
      #pragma unroll
      for (int j = 0; j < 4; ++j){
        float sc = (j < 2) ? inv_maxc : 1.0f;
        bfr[s][4][j] = (_Float16)(wih[(      chs)*32 + 28 + j] * sc * KS);
        bfz[s][4][j] = (_Float16)(wih[(128 + chs)*32 + 28 + j] * sc * KS);
        bfni[s][j]   = (_Float16)(wih[(256 + chs)*32 + 28 + j] * sc * KT);
      }
    }
  }
  const float bR0  = (bih[ch0]     + bhh[ch0]    ) * KS;
  const float bR1  = (bih[ch1]     + bhh[ch1]    ) * KS;
  const float bZ0  = (bih[128+ch0] + bhh[128+ch0]) * KS;
  const float bZ1  = (bih[128+ch1] + bhh[128+ch1]) * KS;
  const float bNI0 = bih[256+ch0] * KT;
  const float bNI1 = bih[256+ch1] * KT;
  const float bNH0 = bhh[256+ch0] * KT;
  const float bNH1 = bhh[256+ch1] * KT;

  // job items (per quad: 4 items)
  int it[4], hp[4];
  #pragma unroll
  for (int r = 0; r < 4; ++r){
    it[r] = perm[q*16 + qd*4 + r];
    hp[r] = hop[it[r]];
  }
  int tmax = max(max(hp[0],hp[1]), max(hp[2],hp[3]));
  tmax = max(tmax, __shfl_xor(tmax, 16, 64));
  tmax = max(tmax, __shfl_xor(tmax, 32, 64));

  // feature-writer lanes: 4 per wave (item = w*4 + lane, one f16x4 each)
  const int  fw_i = w*4 + lane;
  const bool fw   = (lane < 4);
  const int  fw_b = fw ? perm[q*16 + fw_i] : 0;

  __syncthreads();   // pad zeroing complete before feature writes

  // init: h0 (both slices) + features(t=0); prime the feats pipeline
  float hprev0[4], hprev1[4];
  #pragma unroll
  for (int r = 0; r < 4; ++r){
    hprev0[r] = 0.0f;
    hprev1[r] = (ch1 == 127) ? demand[it[r]] * inv_maxc : 0.0f;
    hA[0][(qd*4 + r)*ST + ch0] = (_Float16)hprev0[r];
    hA[0][(qd*4 + r)*ST + ch1] = (_Float16)hprev1[r];
  }
  f16x4 fvreg = (f16x4)0;
  if (fw){
    *(f16x4*)(&hA[0][fw_i*ST + 128]) = feats16[fw_b*ML + 0];
    fvreg = feats16[fw_b*ML + 1];     // feats(t=1), retires during step 0
  }
  __syncthreads();

  for (int t = 0; t < tmax; ++t){
    const int cur = t & 1, nxt = cur ^ 1;
    if (fw){
      *(f16x4*)(&hA[nxt][fw_i*ST + 128]) = fvreg;   // feats(t+1), loaded at t-1
      int tn = t + 2; tn = (tn < ML) ? tn : (ML - 1);
      fvreg = feats16[fw_b*ML + tn];                // in flight across this step
    }

    // one A-load (5 x b128), used by both slices (30 MFMAs)
    f16x8 a[5];
    #pragma unroll
    for (int kc = 0; kc < 5; ++kc)
      a[kc] = *(const f16x8*)(&hA[cur][lm*ST + kc*32 + qd*8]);

    // ---- slice 0 ----
    {
      f32x4 accr  = {bR0, bR0, bR0, bR0};
      f32x4 accz  = {bZ0, bZ0, bZ0, bZ0};
      f32x4 accnh = {bNH0, bNH0, bNH0, bNH0};
      f32x4 accni = {bNI0, bNI0, bNI0, bNI0};
      #pragma unroll
      for (int kc = 0; kc < 5; ++kc){
        accr = __builtin_amdgcn_mfma_f32_16x16x32_f16(a[kc], bfr[0][kc], accr, 0, 0, 0);
        accz = __builtin_amdgcn_mfma_f32_16x16x32_f16(a[kc], bfz[0][kc], accz, 0, 0, 0);
        if (kc < 4)
          accnh = __builtin_amdgcn_mfma_f32_16x16x32_f16(a[kc], bfnh[0][kc], accnh, 0, 0, 0);
        else
          accni = __builtin_amdgcn_mfma_f32_16x16x32_f16(a[kc], bfni[0], accni, 0, 0, 0);
      }
      #pragma unroll
      for (int r = 0; r < 4; ++r){
        float rr = sig2_(accr[r]);
        float zz = sig2_(accz[r]);
        float nn = tanh2_(fmaf(rr, accnh[r], accni[r]));
        float hn = fmaf(zz, hprev0[r] - nn, nn);       // (1-z)*n + z*h
        if (t < hp[r]) hprev0[r] = hn;                 // freeze finished items
        hA[nxt][(qd*4 + r)*ST + ch0] = (_Float16)hprev0[r];
      }
    }
    // ---- slice 1 ----
    {
      f32x4 accr  = {bR1, bR1, bR1, bR1};
      f32x4 accz  = {bZ1, bZ1, bZ1, bZ1};
      f32x4 accnh = {bNH1, bNH1, bNH1, bNH1};
      f32x4 accni = {bNI1, bNI1, bNI1, bNI1};
      #pragma unroll
      for (int kc = 0; kc < 5; ++kc){
        accr = __builtin_amdgcn_mfma_f32_16x16x32_f16(a[kc], bfr[1][kc], accr, 0, 0, 0);
        accz = __builtin_amdgcn_mfma_f32_16x16x32_f16(a[kc], bfz[1][kc], accz, 0, 0, 0);
        if (kc < 4)
          accnh = __builtin_amdgcn_mfma_f32_16x16x32_f16(a[kc], bfnh[1][kc], accnh, 0, 0, 0);
        else
          accni = __builtin_amdgcn_mfma_f32_16x16x32_f16(a[kc], bfni[1], accni, 0, 0, 0);
      }
      #pragma unroll
      for (int r = 0; r < 4; ++r){
        float rr = sig2_(accr[r]);
        float zz = sig2_(accz[r]);
        float nn = tanh2_(fmaf(rr, accnh[r], accni[r]));
        float hn = fmaf(zz, hprev1[r] - nn, nn);       // (1-z)*n + z*h
        if (t < hp[r]) hprev1[r] = hn;                 // freeze finished items
        hA[nxt][(qd*4 + r)*ST + ch1] = (_Float16)hprev1[r];
      }
    }
    __syncthreads();
  }

  // flow write + BN partials (reduce over items = across qd for fixed lm)
  float s0 = 0.f, q0 = 0.f, s1 = 0.f, q1 = 0.f;
  #pragma unroll
  for (int r = 0; r < 4; ++r){
    float v0 = hprev0[r], v1 = hprev1[r];
    flow[it[r]*DP + ch0] = v0;
    flow[it[r]*DP + ch1] = v1;
    s0 += v0;  q0 = fmaf(v0, v0, q0);
    s1 += v1;  q1 = fmaf(v1, v1, q1);
  }
  s0 += __shfl_xor(s0, 16, 64);  s0 += __shfl_xor(s0, 32, 64);
  q0 += __shfl_xor(q0, 16, 64);  q0 += __shfl_xor(q0, 32, 64);
  s1 += __shfl_xor(s1, 16, 64);  s1 += __shfl_xor(s1, 32, 64);
  q1 += __shfl_xor(q1, 16, 64);  q1 += __shfl_xor(q1, 32, 64);
  if (qd == 0){
    atomicAdd(&ws[OFF_SUM + ch0], s0);
    atomicAdd(&ws[OFF_SSQ + ch0], q0);
    atomicAdd(&ws[OFF_SUM + ch1], s1);
    atomicAdd(&ws[OFF_SSQ + ch1], q1);
  }
}

// ---------------------------------------------------------------------------
// BN-finalize + 3-headed MLP via MFMA.
// R21: b1/b2 fragment loads use the lane-ordered w1c/w2c tables --
// 64 lanes x 16 B contiguous per load instruction.
// ---------------------------------------------------------------------------
__launch_bounds__(256, 4)
__global__ void kmlp(const float* __restrict__ flow, const float* __restrict__ ws,
                     const float* __restrict__ gamma, const float* __restrict__ beta,
                     const float* __restrict__ rb1, const float* __restrict__ rb2,
                     const float* __restrict__ rW3, const float* __restrict__ rb3,
                     float* __restrict__ out){
  __shared__ _Float16 x_lds[32*136];
  __shared__ _Float16 h1_lds[32*264];
  __shared__ float aa[DP], bb[DP];
  __shared__ float y_part[4][32];
  const int tid  = threadIdx.x;
  const int w    = tid >> 6;
  const int lane = tid & 63;
  const int lm   = lane & 15;
  const int qd   = lane >> 4;
  const int b0   = blockIdx.x * 32;
  const int u    = blockIdx.y;
  const _Float16* w1 = (const _Float16*)(ws + OFF_W1) + u*(DR*DP);
  const _Float16* w2 = (const _Float16*)(ws + OFF_W2) + u*(DR*DR);

  if (tid < DP){                                // BN finalize (redundant/block)
    float m = ws[OFF_SUM + tid] * (1.0f/BS);
    float q = ws[OFF_SSQ + tid] * (1.0f/BS);
    float rstd = rsqrtf(q - m*m + 1e-5f);
    float a = rstd * gamma[tid];
    aa[tid] = a;
    bb[tid] = fmaf(-m, a, beta[tid]);
  }
  __syncthreads();

  for (int idx = tid; idx < 32*DP; idx += 256){
    int i = idx >> 7, h = idx & 127;
    x_lds[i*136 + h] = (_Float16)fmaf(flow[(b0 + i)*DP + h], aa[h], bb[h]);
  }
  __syncthreads();

  // ---- L1: 32x128 @ 128x256 -> selu -> h1_lds ----
  for (int nt = 0; nt < 4; ++nt){
    const int ng = 4*w + nt;
    const int n  = ng*16 + lm;
    const float bias1 = rb1[u*DR + n];
    f16x8 b1[4];
    #pragma unroll
    for (int kc = 0; kc < 4; ++kc)
      b1[kc] = *(const f16x8*)(w1 + ((ng*4 + kc)*64 + lane)*8);
    #pragma unroll
    for (int mt = 0; mt < 2; ++mt){
      f32x4 acc = {bias1, bias1, bias1, bias1};
      #pragma unroll
      for (int kc = 0; kc < 4; ++kc){
        f16x8 a1 = *(const f16x8*)(&x_lds[(mt*16 + lm)*136 + kc*32 + qd*8]);
        acc = __builtin_amdgcn_mfma_f32_16x16x32_f16(a1, b1[kc], acc, 0, 0, 0);
      }
      #pragma unroll
      for (int r = 0; r < 4; ++r)
        h1_lds[(mt*16 + qd*4 + r)*264 + n] = (_Float16)seluf_(acc[r]);
    }
  }
  __syncthreads();

  // ---- L2: 32x256 @ 256x256 -> selu -> dot w3 (in-wave reduce) ----
  {
    float p[2][4] = {{0.f,0.f,0.f,0.f},{0.f,0.f,0.f,0.f}};
    for (int nt = 0; nt < 4; ++nt){
      const int ng = 4*w + nt;
      const int n  = ng*16 + lm;
      const float bias2 = rb2[u*DR + n];
      const float w3l   = rW3[u*DR + n];
      f16x8 b2[8];
      #pragma unroll
      for (int kc = 0; kc < 8; ++kc)
        b2[kc] = *(const f16x8*)(w2 + ((ng*8 + kc)*64 + lane)*8);
      #pragma unroll
      for (int mt = 0; mt < 2; ++mt){
        f32x4 acc = {bias2, bias2, bias2, bias2};
        #pragma unroll
        for (int kc = 0; kc < 8; ++kc){
          f16x8 a2 = *(const f16x8*)(&h1_lds[(mt*16 + lm)*264 + kc*32 + qd*8]);
          acc = __builtin_amdgcn_mfma_f32_16x16x32_f16(a2, b2[kc], acc, 0, 0, 0);
        }
        #pragma unroll
        for (int r = 0; r < 4; ++r)
          p[mt][r] += seluf_(acc[r]) * w3l;
      }
    }
    #pragma unroll
    for (int mt = 0; mt < 2; ++mt){
      #pragma unroll
      for (int r = 0; r < 4; ++r){
        float v = p[mt][r];
        v += __shfl_xor(v, 1, 64);
        v += __shfl_xor(v, 2, 64);
        v += __shfl_xor(v, 4, 64);
        v += __shfl_xor(v, 8, 64);
        if (lm == 0) y_part[w][mt*16 + qd*4 + r] = v;
      }
    }
  }
  __syncthreads();
  if (tid < 32){
    float y = y_part[0][tid] + y_part[1][tid] + y_part[2][tid] + y_part[3][tid] + rb3[u];
    out[(b0 + tid)*3 + u] = y;
  }
}

extern "C" void kernel_launch(void* const* d_in, const int* in_sizes, int n_in,
                              void* d_out, int out_size, void* d_ws, size_t ws_size,
                              hipStream_t stream){
  const float* demand = (const float*)d_in[0];
  const float* avail  = (const float*)d_in[1];
  const float* capa   = (const float*)d_in[2];
  const float* loss   = (const float*)d_in[3];
  const int*   path   = (const int*)d_in[4];
  const int*   hop    = (const int*)d_in[5];
  const float* wih    = (const float*)d_in[6];
  const float* whh    = (const float*)d_in[7];
  const float* bih    = (const float*)d_in[8];
  const float* bhh    = (const float*)d_in[9];
  const float* gamma  = (const float*)d_in[10];
  const float* beta   = (const float*)d_in[11];
  const float* rW1    = (const float*)d_in[12];
  const float* rb1    = (const float*)d_in[13];
  const float* rW2    = (const float*)d_in[14];
  const float* rb2    = (const float*)d_in[15];
  const float* rW3    = (const float*)d_in[16];
  const float* rb3    = (const float*)d_in[17];
  float* ws  = (float*)d_ws;
  float* out = (float*)d_out;

  prep_all <<<PREP_GRID, 256, 0, stream>>>(path, hop, avail, capa, loss,
                                           whh, rW1, rW2, ws);
  kgru     <<<NJOB, 256, 0, stream>>>(demand, hop, wih, bih, bhh, ws, ws + OFF_FLOW);
  kmlp     <<<dim3(BS/32, 3), 256, 0, stream>>>(ws + OFF_FLOW, ws, gamma, beta,
                                                rb1, rb2, rW3, rb3, out);
}